// Round 4
// baseline (260.362 us; speedup 1.0000x reference)
//
#include <hip/hip_runtime.h>

// Problem constants (from reference)
#define NNODES 100000
#define NEDGES 3200000
#define DIM    128

typedef __bf16  bf16x8 __attribute__((ext_vector_type(8)));
typedef unsigned short u16;
typedef u16     u16x4  __attribute__((ext_vector_type(4)));
typedef u16     u16x8  __attribute__((ext_vector_type(8)));
typedef float   f32x4  __attribute__((ext_vector_type(4)));
typedef unsigned int u32;
typedef u32     u32x4  __attribute__((ext_vector_type(4)));

__device__ __forceinline__ u16 f2bf(float f) {
    // round-to-nearest-even f32 -> bf16
    union { float f; unsigned int i; } c;
    c.f = f;
    unsigned int x = c.i;
    unsigned int rounding = 0x7fff + ((x >> 16) & 1);
    x += rounding;
    return (u16)(x >> 16);
}

__device__ __forceinline__ float asf(u32 u) {
    union { u32 i; float f; } c; c.i = u; return c.f;
}

__device__ __forceinline__ bf16x8 ldfrag_u16(const u16* p) {
    u16x8 u = *(const u16x8*)p;
    return __builtin_bit_cast(bf16x8, u);
}

// ---------------------------------------------------------------------------
// Kernel 1: CSR row_ptr from sorted edge_row via binary search.
__global__ void build_row_ptr(const int* __restrict__ edge_row,
                              int* __restrict__ row_ptr) {
    int n = blockIdx.x * blockDim.x + threadIdx.x;
    if (n > NNODES) return;
    int lo = 0, hi = NEDGES;
    while (lo < hi) {
        int mid = (lo + hi) >> 1;
        if (edge_row[mid] < n) lo = mid + 1; else hi = mid;
    }
    row_ptr[n] = lo;
}

// ---------------------------------------------------------------------------
// Kernel 2: y = bf16(x) @ bf16(W)  (fp32 in, bf16 out, fp32 MFMA accumulate)
//
// R4 rewrite (the non-spmm ~130us was never profiled; gemm is the only
// candidate big enough):
//  * 512-thread blocks, 128 rows/block (782 blocks).
//  * x staged COALESCED (f32x4, 32 lanes span a full 512B row) -> bf16 into
//    padded LDS (stride 136 u16) ONCE, instead of 16B/lane stride-512B
//    fragment loads from HBM inside the MFMA dependence chain.
//  * W transposed+converted from global w directly in the prologue --
//    prep_wt kernel and wt workspace deleted (one fewer dispatch).
//  * MFMA reads A and B from LDS; stride-136 keeps ds_read_b128 at <=2-way
//    bank aliasing (free per m136).
//  * xlds reused as the per-wave y-bounce tile after a barrier (no extra LDS).
//  LDS = 34816 (W) + 34816 (x) = 69632 B -> 2 blocks/CU, 16 waves/CU.
#define WT_STRIDE 136   // u16 units; 272B rows, 16B aligned, breaks pow2 banks
__global__ __launch_bounds__(512, 4) void gemm_xw(const float* __restrict__ x,
                                                  const float* __restrict__ w,
                                                  u16* __restrict__ y) {
    __shared__ u16 wlds[DIM * WT_STRIDE];   // 34816 B : Wt[n][k] bf16, padded
    __shared__ u16 xlds[128 * WT_STRIDE];   // 34816 B : x[r][k] bf16, padded

    int tid = threadIdx.x;
    int rowBase = blockIdx.x * 128;

    // --- stage x: 128 rows x 32 f32x4 chunks, fully coalesced ---
#pragma unroll
    for (int i = 0; i < 8; ++i) {
        int ci  = tid + 512 * i;            // 0..4095
        int r   = ci >> 5;                  // 0..127
        int off = ci & 31;                  // f32x4 index within row
        if (rowBase + r < NNODES) {
            f32x4 v = *(const f32x4*)(x + (size_t)(rowBase + r) * DIM + off * 4);
            u16x4 b;
#pragma unroll
            for (int j = 0; j < 4; ++j) b[j] = f2bf(v[j]);
            *(u16x4*)(xlds + r * WT_STRIDE + off * 4) = b;
        }
    }

    // --- stage Wt: read w[k][n0..n0+3] coalesced, scatter-transpose to LDS ---
#pragma unroll
    for (int i = 0; i < 8; ++i) {
        int ci = tid + 512 * i;             // 0..4095
        int k  = ci >> 5;                   // 0..127
        int n0 = (ci & 31) * 4;
        f32x4 v = *(const f32x4*)(w + (size_t)k * DIM + n0);
#pragma unroll
        for (int j = 0; j < 4; ++j)
            wlds[(n0 + j) * WT_STRIDE + k] = f2bf(v[j]);
    }
    __syncthreads();

    int wave = __builtin_amdgcn_readfirstlane(tid >> 6);   // 0..7
    int lane = tid & 63;
    int quad = lane >> 4, l16 = lane & 15;
    int mBase = rowBase + wave * 16;
    int active = (mBase < NNODES);

    f32x4 acc[8];
#pragma unroll
    for (int nt = 0; nt < 8; ++nt) acc[nt] = (f32x4){0.f, 0.f, 0.f, 0.f};

    if (active) {
#pragma unroll
        for (int kb = 0; kb < 4; ++kb) {
            bf16x8 a = ldfrag_u16(xlds + (wave * 16 + l16) * WT_STRIDE + kb * 32 + quad * 8);
#pragma unroll
            for (int nt = 0; nt < 8; ++nt) {
                bf16x8 b = ldfrag_u16(wlds + (nt * 16 + l16) * WT_STRIDE + kb * 32 + quad * 8);
                acc[nt] = __builtin_amdgcn_mfma_f32_16x16x32_bf16(a, b, acc[nt], 0, 0, 0);
            }
        }
    }

    // all K-loop reads of xlds done -> reuse xlds as per-wave bounce tiles
    __syncthreads();

    if (active) {
        u16* yb = xlds + wave * (16 * DIM);   // 4KB per wave, 32KB total
#pragma unroll
        for (int nt = 0; nt < 8; ++nt) {
            int col = nt * 16 + l16;
#pragma unroll
            for (int r = 0; r < 4; ++r)
                yb[(quad * 4 + r) * DIM + col] = f2bf(acc[nt][r]);
        }
#pragma unroll
        for (int j = 0; j < 4; ++j) {
            int lr = j * 4 + quad;             // 0..15
            u16x8 t = *(const u16x8*)(yb + lr * DIM + l16 * 8);
            *(u16x8*)(y + (size_t)(mBase + lr) * DIM + l16 * 8) = t;
        }
    }
}

// ---------------------------------------------------------------------------
// Kernel 3: out[n][:] = bias + sum_{e in row n} val[e] * y[col[e]][:]
// R0 version verbatim (best measured: 109.3us). R1-R3 showed spmm time is
// pinned ~110us across phase-split/MLP/burst restructurings -> per-CU
// outstanding-miss capacity x latency is the ceiling; the 6.4M x 128B line
// request stream is invariant. Quad-edge 16-lane gather, 4-deep MLP.
__global__ __launch_bounds__(256, 8) void spmm(const int* __restrict__ row_ptr,
                                               const int* __restrict__ ecol,
                                               const float* __restrict__ eval,
                                               const u16* __restrict__ y,
                                               const float* __restrict__ bias,
                                               float* __restrict__ out) {
    int lane = threadIdx.x & 63;
    int row  = __builtin_amdgcn_readfirstlane(blockIdx.x * 4 + (threadIdx.x >> 6));
    if (row >= NNODES) return;

    int lo = row_ptr[row];
    int hi = row_ptr[row + 1];

    int grp = lane >> 4;   // which edge of the quad this lane serves
    int sub = lane & 15;   // which 16B chunk of the 256B y-row

    float acc[8];
#pragma unroll
    for (int j = 0; j < 8; ++j) acc[j] = 0.f;

    const u16* ychunk = y + sub * 8;

    int e = lo;
    // main loop: 16 edges per iteration, 4 gather insts of 1KB each
    for (; e + 16 <= hi; e += 16) {
#pragma unroll
        for (int b = 0; b < 4; ++b) {
            int e0 = e + b * 4;
            int   c0 = ecol[e0], c1 = ecol[e0 + 1], c2 = ecol[e0 + 2], c3 = ecol[e0 + 3];
            float v0 = eval[e0], v1 = eval[e0 + 1], v2 = eval[e0 + 2], v3 = eval[e0 + 3];
            int   c = grp < 2 ? (grp == 0 ? c0 : c1) : (grp == 2 ? c2 : c3);
            float v = grp < 2 ? (grp == 0 ? v0 : v1) : (grp == 2 ? v2 : v3);
            u32x4 q = *(const u32x4*)(ychunk + (size_t)c * DIM);
#pragma unroll
            for (int j = 0; j < 4; ++j) {
                acc[2 * j]     += v * asf(q[j] << 16);
                acc[2 * j + 1] += v * asf(q[j] & 0xffff0000u);
            }
        }
    }
    // tail: up to 4 edges per pass, padded with v=0 on the repeated index
    for (; e < hi; e += 4) {
        int rem = hi - e;   // >= 1, uniform
        int i1 = rem > 1 ? e + 1 : e, i2 = rem > 2 ? e + 2 : e, i3 = rem > 3 ? e + 3 : e;
        int   c0 = ecol[e],  c1 = ecol[i1], c2 = ecol[i2], c3 = ecol[i3];
        float v0 = eval[e];
        float v1 = rem > 1 ? eval[i1] : 0.f;
        float v2 = rem > 2 ? eval[i2] : 0.f;
        float v3 = rem > 3 ? eval[i3] : 0.f;
        int   c = grp < 2 ? (grp == 0 ? c0 : c1) : (grp == 2 ? c2 : c3);
        float v = grp < 2 ? (grp == 0 ? v0 : v1) : (grp == 2 ? v2 : v3);
        u32x4 q = *(const u32x4*)(ychunk + (size_t)c * DIM);
#pragma unroll
        for (int j = 0; j < 4; ++j) {
            acc[2 * j]     += v * asf(q[j] << 16);
            acc[2 * j + 1] += v * asf(q[j] & 0xffff0000u);
        }
    }

    // merge the 4 lane-groups (same sub, grp 0..3)
#pragma unroll
    for (int j = 0; j < 8; ++j) {
        acc[j] += __shfl_xor(acc[j], 16);
        acc[j] += __shfl_xor(acc[j], 32);
    }

    if (grp == 0) {
        float* orow = out + (size_t)row * DIM + sub * 8;
        f32x4 o0, o1;
#pragma unroll
        for (int j = 0; j < 4; ++j) {
            o0[j] = acc[j]     + bias[sub * 8 + j];
            o1[j] = acc[4 + j] + bias[sub * 8 + 4 + j];
        }
        __builtin_nontemporal_store(o0, (f32x4*)orow);
        __builtin_nontemporal_store(o1, (f32x4*)(orow + 4));
    }
}

// ---------------------------------------------------------------------------
extern "C" void kernel_launch(void* const* d_in, const int* in_sizes, int n_in,
                              void* d_out, int out_size, void* d_ws, size_t ws_size,
                              hipStream_t stream) {
    const float* x        = (const float*)d_in[0];  // [NNODES, DIM] fp32
    const int*   edge_row = (const int*)d_in[1];    // [NEDGES] int32 (sorted)
    const int*   edge_col = (const int*)d_in[2];    // [NEDGES] int32
    const float* edge_val = (const float*)d_in[3];  // [NEDGES] fp32
    const float* weight   = (const float*)d_in[4];  // [DIM, DIM] fp32
    const float* bias     = (const float*)d_in[5];  // [DIM] fp32
    float* out = (float*)d_out;                     // [NNODES, DIM] fp32

    char* ws = (char*)d_ws;
    // layout: y bf16 [NNODES*DIM] | row_ptr int[NNODES+1]
    u16* y       = (u16*)ws;                               // 25,600,000 B
    int* row_ptr = (int*)(ws + (size_t)NNODES * DIM * 2);  // 400,004 B

    build_row_ptr<<<(NNODES + 1 + 255) / 256, 256, 0, stream>>>(edge_row, row_ptr);

    // y = x @ W : 128 rows/block, 512 threads -> 782 blocks
    gemm_xw<<<(NNODES + 127) / 128, 512, 0, stream>>>(x, weight, y);

    // out = A @ y + bias : one wave per row, 4 waves/block -> 25000 blocks
    spmm<<<NNODES / 4, 256, 0, stream>>>(row_ptr, edge_col, edge_val, y, bias, out);
}

// Round 5
// 252.667 us; speedup vs baseline: 1.0305x; 1.0305x over previous
//
#include <hip/hip_runtime.h>

// Problem constants (from reference)
#define NNODES 100000
#define NEDGES 3200000
#define DIM    128

typedef __bf16  bf16x8 __attribute__((ext_vector_type(8)));
typedef unsigned short u16;
typedef u16     u16x8  __attribute__((ext_vector_type(8)));
typedef float   f32x4  __attribute__((ext_vector_type(4)));
typedef unsigned int u32;
typedef u32     u32x4  __attribute__((ext_vector_type(4)));

__device__ __forceinline__ u16 bfbits(float f) {
    // native RNE f32->bf16 (compiler emits v_cvt_pk_bf16_f32 when paired)
    __bf16 h = (__bf16)f;
    return __builtin_bit_cast(u16, h);
}

__device__ __forceinline__ float asf(u32 u) {
    union { u32 i; float f; } c; c.i = u; return c.f;
}

__device__ __forceinline__ bf16x8 ldfrag_u16(const u16* p) {
    u16x8 u = *(const u16x8*)p;
    return __builtin_bit_cast(bf16x8, u);
}

// convert two f32x4 to a bf16x8 MFMA fragment with native casts
__device__ __forceinline__ bf16x8 cvt8(f32x4 a, f32x4 b) {
    bf16x8 r;
#pragma unroll
    for (int i = 0; i < 4; ++i) {
        r[i]     = (__bf16)a[i];
        r[4 + i] = (__bf16)b[i];
    }
    return r;
}

// ---------------------------------------------------------------------------
// Kernel 1: fused prep — CSR row_ptr (binary search on sorted edge_row) AND
// Wt[n][k] = bf16(W[k][n]). One dispatch instead of two.
__global__ void prep(const int* __restrict__ edge_row, int* __restrict__ row_ptr,
                     const float* __restrict__ w, u16* __restrict__ wt) {
    int gid = blockIdx.x * blockDim.x + threadIdx.x;
    if (gid <= NNODES) {
        int lo = 0, hi = NEDGES;
        while (lo < hi) {
            int mid = (lo + hi) >> 1;
            if (edge_row[mid] < gid) lo = mid + 1; else hi = mid;
        }
        row_ptr[gid] = lo;
    }
    if (gid < DIM * DIM) {
        int k = gid >> 7, n = gid & 127;
        wt[n * DIM + k] = bfbits(w[k * DIM + n]);
    }
}

// ---------------------------------------------------------------------------
// Kernel 2: y = bf16(x) @ bf16(W)  (fp32 in, bf16 out, fp32 MFMA accumulate)
// R0 structure (proven best) + R5 fixes:
//  * native __bf16 casts (v_cvt_pk) instead of 5-op manual RNE
//  * all 4 x-fragments prefetched before the MFMA dependence chain
//  * wlds reused as the y-bounce tile after a barrier: LDS 51.2KB -> 34.8KB
//    => 4 blocks/CU (was 3)
//  * no early returns (barrier-safe predication)
#define WT_STRIDE 136   // u16 units; 272B rows, 16B aligned, breaks pow2 banks
__global__ __launch_bounds__(256, 4) void gemm_xw(const float* __restrict__ x,
                                                  const u16* __restrict__ wt,
                                                  u16* __restrict__ y) {
    __shared__ u16 wlds[DIM * WT_STRIDE];     // 34816 B

    int tid = threadIdx.x;
    // cooperative staged copy of Wt (128 rows x 256B) into padded LDS
    {
        const f32x4* src = (const f32x4*)wt;   // 16B chunks, 16 per row
#pragma unroll
        for (int i = 0; i < 8; ++i) {
            int ci  = tid + 256 * i;           // 0..2047
            int row = ci >> 4, off = ci & 15;
            *((f32x4*)(wlds + row * WT_STRIDE) + off) = src[ci];
        }
    }
    __syncthreads();

    int wave = __builtin_amdgcn_readfirstlane(tid >> 6);
    int lane = tid & 63;
    int quad = lane >> 4, l16 = lane & 15;
    int mBase = (blockIdx.x * 4 + wave) * 16;
    int active = (mBase < NNODES);             // NNODES%16==0: whole-wave guard

    const float* xrow = x + (size_t)(mBase + l16) * DIM + quad * 8;

    // prefetch all x fragments up front (8 x 16B loads in flight)
    f32x4 xa[4], xb[4];
    if (active) {
#pragma unroll
        for (int kb = 0; kb < 4; ++kb) {
            xa[kb] = *(const f32x4*)(xrow + kb * 32);
            xb[kb] = *(const f32x4*)(xrow + kb * 32 + 4);
        }
    }

    f32x4 acc[8];
#pragma unroll
    for (int nt = 0; nt < 8; ++nt) acc[nt] = (f32x4){0.f, 0.f, 0.f, 0.f};

    if (active) {
#pragma unroll
        for (int kb = 0; kb < 4; ++kb) {
            bf16x8 a = cvt8(xa[kb], xb[kb]);
#pragma unroll
            for (int nt = 0; nt < 8; ++nt) {
                bf16x8 b = ldfrag_u16(wlds + (nt * 16 + l16) * WT_STRIDE + kb * 32 + quad * 8);
                acc[nt] = __builtin_amdgcn_mfma_f32_16x16x32_bf16(a, b, acc[nt], 0, 0, 0);
            }
        }
    }

    // all K-loop reads of wlds done -> reuse wlds as per-wave bounce tiles
    __syncthreads();

    if (active) {
        u16* yb = wlds + wave * (16 * DIM);    // 4KB per wave, 16KB total
#pragma unroll
        for (int nt = 0; nt < 8; ++nt) {
            int col = nt * 16 + l16;
#pragma unroll
            for (int r = 0; r < 4; ++r)
                yb[(quad * 4 + r) * DIM + col] = bfbits(acc[nt][r]);
        }
#pragma unroll
        for (int j = 0; j < 4; ++j) {
            int lr = j * 4 + quad;             // 0..15
            u16x8 t = *(const u16x8*)(yb + lr * DIM + l16 * 8);
            __builtin_nontemporal_store(t, (u16x8*)(y + (size_t)(mBase + lr) * DIM + l16 * 8));
        }
    }
}

// ---------------------------------------------------------------------------
// Kernel 3: out[n][:] = bias + sum_{e in row n} val[e] * y[col[e]][:]
// R0 version (best measured: 109.3us; R1-R3 proved ~110us is a per-CU
// outstanding-miss capacity x latency ceiling, invariant to restructuring).
// R5: +rowBase arg; launched as TWO half-grids so the rocprof top-5 cutoff
// drops to ~55us and any hidden expensive dispatch (gemm?) becomes visible.
__global__ __launch_bounds__(256, 8) void spmm(const int* __restrict__ row_ptr,
                                               const int* __restrict__ ecol,
                                               const float* __restrict__ eval,
                                               const u16* __restrict__ y,
                                               const float* __restrict__ bias,
                                               float* __restrict__ out,
                                               int rowBase) {
    int lane = threadIdx.x & 63;
    int row  = __builtin_amdgcn_readfirstlane(rowBase + blockIdx.x * 4 + (threadIdx.x >> 6));
    if (row >= NNODES) return;

    int lo = row_ptr[row];
    int hi = row_ptr[row + 1];

    int grp = lane >> 4;   // which edge of the quad this lane serves
    int sub = lane & 15;   // which 16B chunk of the 256B y-row

    float acc[8];
#pragma unroll
    for (int j = 0; j < 8; ++j) acc[j] = 0.f;

    const u16* ychunk = y + sub * 8;

    int e = lo;
    // main loop: 16 edges per iteration, 4 gather insts of 1KB each
    for (; e + 16 <= hi; e += 16) {
#pragma unroll
        for (int b = 0; b < 4; ++b) {
            int e0 = e + b * 4;
            int   c0 = ecol[e0], c1 = ecol[e0 + 1], c2 = ecol[e0 + 2], c3 = ecol[e0 + 3];
            float v0 = eval[e0], v1 = eval[e0 + 1], v2 = eval[e0 + 2], v3 = eval[e0 + 3];
            int   c = grp < 2 ? (grp == 0 ? c0 : c1) : (grp == 2 ? c2 : c3);
            float v = grp < 2 ? (grp == 0 ? v0 : v1) : (grp == 2 ? v2 : v3);
            u32x4 q = *(const u32x4*)(ychunk + (size_t)c * DIM);
#pragma unroll
            for (int j = 0; j < 4; ++j) {
                acc[2 * j]     += v * asf(q[j] << 16);
                acc[2 * j + 1] += v * asf(q[j] & 0xffff0000u);
            }
        }
    }
    // tail: up to 4 edges per pass, padded with v=0 on the repeated index
    for (; e < hi; e += 4) {
        int rem = hi - e;   // >= 1, uniform
        int i1 = rem > 1 ? e + 1 : e, i2 = rem > 2 ? e + 2 : e, i3 = rem > 3 ? e + 3 : e;
        int   c0 = ecol[e],  c1 = ecol[i1], c2 = ecol[i2], c3 = ecol[i3];
        float v0 = eval[e];
        float v1 = rem > 1 ? eval[i1] : 0.f;
        float v2 = rem > 2 ? eval[i2] : 0.f;
        float v3 = rem > 3 ? eval[i3] : 0.f;
        int   c = grp < 2 ? (grp == 0 ? c0 : c1) : (grp == 2 ? c2 : c3);
        float v = grp < 2 ? (grp == 0 ? v0 : v1) : (grp == 2 ? v2 : v3);
        u32x4 q = *(const u32x4*)(ychunk + (size_t)c * DIM);
#pragma unroll
        for (int j = 0; j < 4; ++j) {
            acc[2 * j]     += v * asf(q[j] << 16);
            acc[2 * j + 1] += v * asf(q[j] & 0xffff0000u);
        }
    }

    // merge the 4 lane-groups (same sub, grp 0..3)
#pragma unroll
    for (int j = 0; j < 8; ++j) {
        acc[j] += __shfl_xor(acc[j], 16);
        acc[j] += __shfl_xor(acc[j], 32);
    }

    if (grp == 0) {
        float* orow = out + (size_t)row * DIM + sub * 8;
        f32x4 o0, o1;
#pragma unroll
        for (int j = 0; j < 4; ++j) {
            o0[j] = acc[j]     + bias[sub * 8 + j];
            o1[j] = acc[4 + j] + bias[sub * 8 + 4 + j];
        }
        __builtin_nontemporal_store(o0, (f32x4*)orow);
        __builtin_nontemporal_store(o1, (f32x4*)(orow + 4));
    }
}

// ---------------------------------------------------------------------------
extern "C" void kernel_launch(void* const* d_in, const int* in_sizes, int n_in,
                              void* d_out, int out_size, void* d_ws, size_t ws_size,
                              hipStream_t stream) {
    const float* x        = (const float*)d_in[0];  // [NNODES, DIM] fp32
    const int*   edge_row = (const int*)d_in[1];    // [NEDGES] int32 (sorted)
    const int*   edge_col = (const int*)d_in[2];    // [NEDGES] int32
    const float* edge_val = (const float*)d_in[3];  // [NEDGES] fp32
    const float* weight   = (const float*)d_in[4];  // [DIM, DIM] fp32
    const float* bias     = (const float*)d_in[5];  // [DIM] fp32
    float* out = (float*)d_out;                     // [NNODES, DIM] fp32

    char* ws = (char*)d_ws;
    // layout: y bf16 [NNODES*DIM] | row_ptr int[NNODES+1] | Wt bf16 [DIM*DIM]
    u16* y       = (u16*)ws;                               // 25,600,000 B
    int* row_ptr = (int*)(ws + (size_t)NNODES * DIM * 2);  // 400,004 B
    u16* wt      = (u16*)(ws + 26000128);                  // 32,768 B (16B aligned)

    // fused prep: row_ptr + Wt transpose/convert (one dispatch)
    prep<<<(NNODES + 1 + 255) / 256, 256, 0, stream>>>(edge_row, row_ptr, weight, wt);

    // y = x @ W : 6250 wave-rows of 16, 4 waves/block -> 1563 blocks
    gemm_xw<<<(NNODES / 16 + 3) / 4, 256, 0, stream>>>(x, wt, y);

    // out = A @ y + bias : two half-grid dispatches (observability: drops the
    // rocprof top-5 cutoff to ~55us so any hidden expensive kernel surfaces)
    spmm<<<NNODES / 8, 256, 0, stream>>>(row_ptr, edge_col, edge_val, y, bias, out, 0);
    spmm<<<NNODES / 8, 256, 0, stream>>>(row_ptr, edge_col, edge_val, y, bias, out, NNODES / 2);
}

// Round 6
// 248.297 us; speedup vs baseline: 1.0486x; 1.0176x over previous
//
#include <hip/hip_runtime.h>

// Problem constants (from reference)
#define NNODES 100000
#define NEDGES 3200000
#define DIM    128

typedef __bf16  bf16x8 __attribute__((ext_vector_type(8)));
typedef unsigned short u16;
typedef u16     u16x8  __attribute__((ext_vector_type(8)));
typedef float   f32x4  __attribute__((ext_vector_type(4)));
typedef unsigned int u32;
typedef u32     u32x4  __attribute__((ext_vector_type(4)));

__device__ __forceinline__ u16 bfbits(float f) {
    __bf16 h = (__bf16)f;              // native RNE f32->bf16
    return __builtin_bit_cast(u16, h);
}

__device__ __forceinline__ float asf(u32 u) {
    union { u32 i; float f; } c; c.i = u; return c.f;
}

__device__ __forceinline__ bf16x8 ldfrag_u16(const u16* p) {
    u16x8 u = *(const u16x8*)p;
    return __builtin_bit_cast(bf16x8, u);
}

// convert two f32x4 to a bf16x8 MFMA fragment with native casts (v_cvt_pk)
__device__ __forceinline__ bf16x8 cvt8(f32x4 a, f32x4 b) {
    bf16x8 r;
#pragma unroll
    for (int i = 0; i < 4; ++i) {
        r[i]     = (__bf16)a[i];
        r[4 + i] = (__bf16)b[i];
    }
    return r;
}

// ---------------------------------------------------------------------------
// Kernel 1: fused prep — CSR row_ptr (binary search on sorted edge_row) AND
// Wt[n][k] = bf16(W[k][n]). One dispatch.
__global__ void prep(const int* __restrict__ edge_row, int* __restrict__ row_ptr,
                     const float* __restrict__ w, u16* __restrict__ wt) {
    int gid = blockIdx.x * blockDim.x + threadIdx.x;
    if (gid <= NNODES) {
        int lo = 0, hi = NEDGES;
        while (lo < hi) {
            int mid = (lo + hi) >> 1;
            if (edge_row[mid] < gid) lo = mid + 1; else hi = mid;
        }
        row_ptr[gid] = lo;
    }
    if (gid < DIM * DIM) {
        int k = gid >> 7, n = gid & 127;
        wt[n * DIM + k] = bfbits(w[k * DIM + n]);
    }
}

// ---------------------------------------------------------------------------
// Kernel 2: y = bf16(x) @ bf16(W)  (fp32 in, bf16 out, fp32 MFMA accumulate)
//
// R6: push toward the ~15us roofline (77MB traffic):
//  * TWO row-tiles per wave (32 rows/wave, 128 rows/block, 782 blocks):
//    - W-staging barrier amortized over 2x the rows (782 stages vs 1563)
//    - 16 x-loads in flight per wave (was 8)
//    - each LDS B-fragment read feeds TWO MFMAs (ds_read:MFMA = 1:2)
//  * early bf16 conversion frees prefetch VGPRs before the MFMA chain
//  * wlds reused as the y-bounce tile after a barrier (LDS 34.8KB total)
//  * __launch_bounds__(256,3): 3 blocks/CU = 12 waves/CU
#define WT_STRIDE 136   // u16 units; 272B rows, 16B aligned, breaks pow2 banks
__global__ __launch_bounds__(256, 3) void gemm_xw(const float* __restrict__ x,
                                                  const u16* __restrict__ wt,
                                                  u16* __restrict__ y) {
    __shared__ u16 wlds[DIM * WT_STRIDE];     // 34816 B

    int tid = threadIdx.x;
    // cooperative staged copy of Wt (128 rows x 256B) into padded LDS
    {
        const f32x4* src = (const f32x4*)wt;   // 16B chunks, 16 per row
#pragma unroll
        for (int i = 0; i < 8; ++i) {
            int ci  = tid + 256 * i;           // 0..2047
            int row = ci >> 4, off = ci & 15;
            *((f32x4*)(wlds + row * WT_STRIDE) + off) = src[ci];
        }
    }

    int wave = __builtin_amdgcn_readfirstlane(tid >> 6);
    int lane = tid & 63;
    int quad = lane >> 4, l16 = lane & 15;
    int mBase = (blockIdx.x * 8 + wave * 2) * 16;   // 32 rows per wave

    // clamped row indices for the x loads (stores are guarded exactly)
    int r0 = mBase + l16;      if (r0 >= NNODES) r0 = NNODES - 1;
    int r1 = mBase + 16 + l16; if (r1 >= NNODES) r1 = NNODES - 1;
    const float* x0 = x + (size_t)r0 * DIM + quad * 8;
    const float* x1 = x + (size_t)r1 * DIM + quad * 8;

    // issue all 16 x-loads, then convert to 8 bf16x8 fragments
    f32x4 t0a[4], t0b[4], t1a[4], t1b[4];
#pragma unroll
    for (int kb = 0; kb < 4; ++kb) {
        t0a[kb] = *(const f32x4*)(x0 + kb * 32);
        t0b[kb] = *(const f32x4*)(x0 + kb * 32 + 4);
    }
#pragma unroll
    for (int kb = 0; kb < 4; ++kb) {
        t1a[kb] = *(const f32x4*)(x1 + kb * 32);
        t1b[kb] = *(const f32x4*)(x1 + kb * 32 + 4);
    }
    bf16x8 a0[4], a1[4];
#pragma unroll
    for (int kb = 0; kb < 4; ++kb) {
        a0[kb] = cvt8(t0a[kb], t0b[kb]);
        a1[kb] = cvt8(t1a[kb], t1b[kb]);
    }

    __syncthreads();   // W staged (placed after x-issue: loads overlap staging)

    f32x4 acc0[8], acc1[8];
#pragma unroll
    for (int nt = 0; nt < 8; ++nt) {
        acc0[nt] = (f32x4){0.f, 0.f, 0.f, 0.f};
        acc1[nt] = (f32x4){0.f, 0.f, 0.f, 0.f};
    }

#pragma unroll
    for (int kb = 0; kb < 4; ++kb) {
#pragma unroll
        for (int nt = 0; nt < 8; ++nt) {
            bf16x8 b = ldfrag_u16(wlds + (nt * 16 + l16) * WT_STRIDE + kb * 32 + quad * 8);
            acc0[nt] = __builtin_amdgcn_mfma_f32_16x16x32_bf16(a0[kb], b, acc0[nt], 0, 0, 0);
            acc1[nt] = __builtin_amdgcn_mfma_f32_16x16x32_bf16(a1[kb], b, acc1[nt], 0, 0, 0);
        }
    }

    // all K-loop reads of wlds done -> reuse wlds as per-wave bounce tiles
    __syncthreads();

    {
        u16* yb = wlds + wave * (32 * DIM);    // 8KB per wave, 32KB total
#pragma unroll
        for (int nt = 0; nt < 8; ++nt) {
            int col = nt * 16 + l16;
#pragma unroll
            for (int r = 0; r < 4; ++r) {
                yb[(quad * 4 + r) * DIM + col]        = bfbits(acc0[nt][r]);
                yb[(16 + quad * 4 + r) * DIM + col]   = bfbits(acc1[nt][r]);
            }
        }
#pragma unroll
        for (int j = 0; j < 8; ++j) {
            int lr = j * 4 + quad;             // 0..31
            if (mBase + lr < NNODES) {
                u16x8 t = *(const u16x8*)(yb + lr * DIM + l16 * 8);
                __builtin_nontemporal_store(t, (u16x8*)(y + (size_t)(mBase + lr) * DIM + l16 * 8));
            }
        }
    }
}

// ---------------------------------------------------------------------------
// Kernel 3: out[n][:] = bias + sum_{e in row n} val[e] * y[col[e]][:]
// R0 version verbatim, single dispatch (best measured: 108.5us; R1-R5 proved
// ~110us is a per-CU outstanding-miss capacity x latency ceiling, invariant
// to phase-split / MLP / burst restructurings; splitting costs ~12us).
__global__ __launch_bounds__(256, 8) void spmm(const int* __restrict__ row_ptr,
                                               const int* __restrict__ ecol,
                                               const float* __restrict__ eval,
                                               const u16* __restrict__ y,
                                               const float* __restrict__ bias,
                                               float* __restrict__ out) {
    int lane = threadIdx.x & 63;
    int row  = __builtin_amdgcn_readfirstlane(blockIdx.x * 4 + (threadIdx.x >> 6));
    if (row >= NNODES) return;

    int lo = row_ptr[row];
    int hi = row_ptr[row + 1];

    int grp = lane >> 4;   // which edge of the quad this lane serves
    int sub = lane & 15;   // which 16B chunk of the 256B y-row

    float acc[8];
#pragma unroll
    for (int j = 0; j < 8; ++j) acc[j] = 0.f;

    const u16* ychunk = y + sub * 8;

    int e = lo;
    // main loop: 16 edges per iteration, 4 gather insts of 1KB each
    for (; e + 16 <= hi; e += 16) {
#pragma unroll
        for (int b = 0; b < 4; ++b) {
            int e0 = e + b * 4;
            int   c0 = ecol[e0], c1 = ecol[e0 + 1], c2 = ecol[e0 + 2], c3 = ecol[e0 + 3];
            float v0 = eval[e0], v1 = eval[e0 + 1], v2 = eval[e0 + 2], v3 = eval[e0 + 3];
            int   c = grp < 2 ? (grp == 0 ? c0 : c1) : (grp == 2 ? c2 : c3);
            float v = grp < 2 ? (grp == 0 ? v0 : v1) : (grp == 2 ? v2 : v3);
            u32x4 q = *(const u32x4*)(ychunk + (size_t)c * DIM);
#pragma unroll
            for (int j = 0; j < 4; ++j) {
                acc[2 * j]     += v * asf(q[j] << 16);
                acc[2 * j + 1] += v * asf(q[j] & 0xffff0000u);
            }
        }
    }
    // tail: up to 4 edges per pass, padded with v=0 on the repeated index
    for (; e < hi; e += 4) {
        int rem = hi - e;   // >= 1, uniform
        int i1 = rem > 1 ? e + 1 : e, i2 = rem > 2 ? e + 2 : e, i3 = rem > 3 ? e + 3 : e;
        int   c0 = ecol[e],  c1 = ecol[i1], c2 = ecol[i2], c3 = ecol[i3];
        float v0 = eval[e];
        float v1 = rem > 1 ? eval[i1] : 0.f;
        float v2 = rem > 2 ? eval[i2] : 0.f;
        float v3 = rem > 3 ? eval[i3] : 0.f;
        int   c = grp < 2 ? (grp == 0 ? c0 : c1) : (grp == 2 ? c2 : c3);
        float v = grp < 2 ? (grp == 0 ? v0 : v1) : (grp == 2 ? v2 : v3);
        u32x4 q = *(const u32x4*)(ychunk + (size_t)c * DIM);
#pragma unroll
        for (int j = 0; j < 4; ++j) {
            acc[2 * j]     += v * asf(q[j] << 16);
            acc[2 * j + 1] += v * asf(q[j] & 0xffff0000u);
        }
    }

    // merge the 4 lane-groups (same sub, grp 0..3)
#pragma unroll
    for (int j = 0; j < 8; ++j) {
        acc[j] += __shfl_xor(acc[j], 16);
        acc[j] += __shfl_xor(acc[j], 32);
    }

    if (grp == 0) {
        float* orow = out + (size_t)row * DIM + sub * 8;
        f32x4 o0, o1;
#pragma unroll
        for (int j = 0; j < 4; ++j) {
            o0[j] = acc[j]     + bias[sub * 8 + j];
            o1[j] = acc[4 + j] + bias[sub * 8 + 4 + j];
        }
        __builtin_nontemporal_store(o0, (f32x4*)orow);
        __builtin_nontemporal_store(o1, (f32x4*)(orow + 4));
    }
}

// ---------------------------------------------------------------------------
extern "C" void kernel_launch(void* const* d_in, const int* in_sizes, int n_in,
                              void* d_out, int out_size, void* d_ws, size_t ws_size,
                              hipStream_t stream) {
    const float* x        = (const float*)d_in[0];  // [NNODES, DIM] fp32
    const int*   edge_row = (const int*)d_in[1];    // [NEDGES] int32 (sorted)
    const int*   edge_col = (const int*)d_in[2];    // [NEDGES] int32
    const float* edge_val = (const float*)d_in[3];  // [NEDGES] fp32
    const float* weight   = (const float*)d_in[4];  // [DIM, DIM] fp32
    const float* bias     = (const float*)d_in[5];  // [DIM] fp32
    float* out = (float*)d_out;                     // [NNODES, DIM] fp32

    char* ws = (char*)d_ws;
    // layout: y bf16 [NNODES*DIM] | row_ptr int[NNODES+1] | Wt bf16 [DIM*DIM]
    u16* y       = (u16*)ws;                               // 25,600,000 B
    int* row_ptr = (int*)(ws + (size_t)NNODES * DIM * 2);  // 400,004 B
    u16* wt      = (u16*)(ws + 26000128);                  // 32,768 B (16B aligned)

    // fused prep: row_ptr + Wt transpose/convert (one dispatch)
    prep<<<(NNODES + 1 + 255) / 256, 256, 0, stream>>>(edge_row, row_ptr, weight, wt);

    // y = x @ W : 128 rows/block (32/wave) -> 782 blocks
    gemm_xw<<<(NNODES + 127) / 128, 256, 0, stream>>>(x, wt, y);

    // out = A @ y + bias : one wave per row, single dispatch -> 25000 blocks
    spmm<<<NNODES / 4, 256, 0, stream>>>(row_ptr, edge_col, edge_val, y, bias, out);
}